// Round 6
// baseline (378.824 us; speedup 1.0000x reference)
//
#include <hip/hip_runtime.h>
#include <hip/hip_fp16.h>
#include <cmath>

// ---------------------------------------------------------------------------
// Self_Attention: B=8, C=256, C_=32, H=W=64, N=4096, GAMMA=1.0
// R10: barrier-free register-P pass2 (the R5-R9 barrier pipeline is
// phase-locked: pipes serialize, util stuck ~20% at any occupancy).
//   - 8 waves = (js 0..3 j-slice x ch 0..1 c-half); each wave computes S
//     ONCE for its 1024-j slice (only x2 redundancy across c-halves),
//     keeps P in regs, accumulates partial O(64i x 128c) over its slice.
//   - O-MFMA 16x16x32: A = hm b128 row-gather (16 rows x full 64B line,
//     L1-BW-optimal; fixes R7's half-wasted b64s), B = P-frag built from
//     the S output via 8 shfl + 4 selects per 16i x 32j tile.
//   - NO LDS / NO barriers in the main loop -> waves free-run, pipes
//     overlap across the 2 waves/SIMD.  LB(512,2): no forced spills.
//   - j-sum partials reduced across js-waves via 64KB swizzled LDS
//     epilogue (4 rounds, once per block).
// ws: xt 16M | wf 256K | ft 2M | gt 2M | hm 16M | shl 128K
// ---------------------------------------------------------------------------

#define BN 8
#define CC 256
#define CQ 32
#define NN 4096

typedef _Float16 half8 __attribute__((ext_vector_type(8)));
typedef _Float16 half4v __attribute__((ext_vector_type(4)));
typedef _Float16 half2v __attribute__((ext_vector_type(2)));
typedef float f32x4 __attribute__((ext_vector_type(4)));
typedef int intx4 __attribute__((ext_vector_type(4)));

static __device__ __forceinline__ float fexp2(float x) {
    return __builtin_amdgcn_exp2f(x);
}

#define LOG2E 1.44269504f
#define SHIFT2 28.8539008f   /* 20 * log2(e) */

// --------------------------------------------------------------------------
// K1: transpose + cvt x[b][c][n] f32 -> xt[b][n][c] f16.  64n x 64c tiles.
// Tail blocks (gid >= 2048) do the weight f32->f16 conversion (fused cvtw).
// --------------------------------------------------------------------------
__global__ __launch_bounds__(256) void transpose_kernel(
    const float* __restrict__ x, __half* __restrict__ xt,
    const float* __restrict__ fw, const float* __restrict__ gw,
    const float* __restrict__ hw, __half* __restrict__ wf16)
{
    const int gid = blockIdx.x;

    if (gid >= 2048) {
        int i = (gid - 2048) * 256 + threadIdx.x;
        float v;
        if (i < 8192)       v = fw[i];
        else if (i < 16384) v = gw[i - 8192];
        else                v = hw[i - 16384];
        wf16[i] = __float2half(v);
        return;
    }

    const int b = gid & 7, rest = gid >> 3;
    const int n0 = (rest & 63) * 64;
    const int c0 = (rest >> 6) * 64;
    const int tid = threadIdx.x;

    __shared__ float T[64 * 65];

    const float* xb = x + ((size_t)b * CC + c0) * NN + n0;
    const int u  = tid >> 4;          // 0..15
    const int n4 = (tid & 15) * 4;
#pragma unroll
    for (int r = 0; r < 4; ++r) {
        int c = r * 16 + u;
        f32x4 v = __builtin_nontemporal_load((const f32x4*)(xb + (size_t)c * NN + n4));
        T[c * 65 + n4 + 0] = v.x;
        T[c * 65 + n4 + 1] = v.y;
        T[c * 65 + n4 + 2] = v.z;
        T[c * 65 + n4 + 3] = v.w;
    }
    __syncthreads();

    const int lane = tid & 63, w = tid >> 6;
    const int n  = w * 16 + (lane >> 2);
    const int cc = (lane & 3) * 16;
    half8 o0, o1;
#pragma unroll
    for (int k = 0; k < 8; ++k) {
        o0[k] = (_Float16)T[(cc + k) * 65 + n];
        o1[k] = (_Float16)T[(cc + 8 + k) * 65 + n];
    }
    __half* dst = xt + ((size_t)b * NN + n0 + n) * CC + c0 + cc;
    *(half8*)(void*)dst = o0;
    *(half8*)(void*)(dst + 8) = o1;
}

// --------------------------------------------------------------------------
// K2: MFMA projections. 1D grid 2560: b = gid&7, then (nt 0..63, ot 0..4).
// --------------------------------------------------------------------------
__global__ __launch_bounds__(256) void proj_kernel(
    const __half* __restrict__ xt, const __half* __restrict__ wf16,
    const float* __restrict__ fb, const float* __restrict__ gb,
    const float* __restrict__ hb,
    __half* __restrict__ ft, __half* __restrict__ gt, __half* __restrict__ hm)
{
    const int tid = threadIdx.x;
    const int w = tid >> 6, lane = tid & 63, col = lane & 15, q = lane >> 4;
    const int gid = blockIdx.x;
    const int b = gid & 7, rest = gid >> 3;
    const int n0 = (rest & 63) * 64;
    const int ot = rest >> 6;          // 0..4

    const __half* xtb  = xt + (size_t)b * NN * CC;
    const __half* fw16 = wf16;
    const __half* gw16 = wf16 + 8192;
    const __half* hw16 = wf16 + 16384;

    f32x4 acc[4];
#pragma unroll
    for (int mt = 0; mt < 4; ++mt) acc[mt] = (f32x4){0.f, 0.f, 0.f, 0.f};

    if (ot == 0) {
        const int pix = n0 + 16 * w + col;
#pragma unroll
        for (int ks = 0; ks < 8; ++ks) {
            half8 bf = *(const half8*)(const void*)(xtb + (size_t)pix * CC + ks * 32 + q * 8);
#pragma unroll
            for (int mt = 0; mt < 4; ++mt) {
                const __half* wp = (mt < 2) ? (fw16 + (16 * mt + col) * CC)
                                            : (gw16 + (16 * (mt - 2) + col) * CC);
                half8 af = *(const half8*)(const void*)(wp + ks * 32 + q * 8);
                acc[mt] = __builtin_amdgcn_mfma_f32_16x16x32_f16(af, bf, acc[mt], 0, 0, 0);
            }
        }
#pragma unroll
        for (int mt = 0; mt < 4; ++mt) {
            const int mtl = mt & 1;
            const float* bsel = (mt < 2) ? fb : gb;
            __half* dsel = (mt < 2) ? ft : gt;
            half4v hv;
#pragma unroll
            for (int r = 0; r < 4; ++r)
                hv[r] = (_Float16)(acc[mt][r] + bsel[16 * mtl + 4 * q + r]);
            *(half4v*)(void*)(dsel + ((size_t)b * NN + pix) * CQ + 16 * mtl + 4 * q) = hv;
        }
    } else {
        const int c = (ot - 1) * 64 + 16 * w + col;
#pragma unroll
        for (int ks = 0; ks < 8; ++ks) {
            half8 bf = *(const half8*)(const void*)(hw16 + (size_t)c * CC + ks * 32 + q * 8);
#pragma unroll
            for (int mt = 0; mt < 4; ++mt) {
                half8 af = *(const half8*)(const void*)(xtb + (size_t)(n0 + 16 * mt + col) * CC + ks * 32 + q * 8);
                acc[mt] = __builtin_amdgcn_mfma_f32_16x16x32_f16(af, bf, acc[mt], 0, 0, 0);
            }
        }
        const float bias = hb[c];
#pragma unroll
        for (int mt = 0; mt < 4; ++mt) {
            half4v hv;
#pragma unroll
            for (int r = 0; r < 4; ++r)
                hv[r] = (_Float16)(acc[mt][r] + bias);
            *(half4v*)(void*)(hm + ((size_t)b * CC + c) * NN + n0 + 16 * mt + 4 * q) = hv;
        }
    }
}

// --------------------------------------------------------------------------
// K3: per-column softmax log-denominator with constant shift:
// shl[b][j] = -log2( sum_i exp2(S_ij*log2e - SHIFT2) ) - SHIFT2
// 2x i-unroll: two independent MFMAs in flight.
// --------------------------------------------------------------------------
__global__ __launch_bounds__(256) void pass1_kernel(
    const __half* __restrict__ ft, const __half* __restrict__ gt,
    float* __restrict__ shl)
{
    const int tid = threadIdx.x;
    const int w = tid >> 6, lane = tid & 63, col = lane & 15, q = lane >> 4;
    const int gid = blockIdx.x;
    const int b = gid & 7;
    const int jg = (gid >> 3) * 64 + 16 * w + col;

    const __half* fbase = ft + (size_t)b * NN * CQ;
    half8 gfrag = *(const half8*)(const void*)(gt + ((size_t)b * NN + jg) * CQ + q * 8);

    float a0 = 0.f, a1 = 0.f, a2 = 0.f, a3 = 0.f;
    const f32x4 zero = {0.f, 0.f, 0.f, 0.f};

    half8 a0v = *(const half8*)(const void*)(fbase + (size_t)col * CQ + q * 8);
    half8 a1v = *(const half8*)(const void*)(fbase + (size_t)(16 + col) * CQ + q * 8);
    for (int i0 = 0; i0 < NN; i0 += 32) {
        int i_n = (i0 + 32) & (NN - 1);
        half8 a2v = *(const half8*)(const void*)(fbase + (size_t)(i_n + col) * CQ + q * 8);
        half8 a3v = *(const half8*)(const void*)(fbase + (size_t)(i_n + 16 + col) * CQ + q * 8);
        f32x4 d0 = __builtin_amdgcn_mfma_f32_16x16x32_f16(a0v, gfrag, zero, 0, 0, 0);
        f32x4 d1 = __builtin_amdgcn_mfma_f32_16x16x32_f16(a1v, gfrag, zero, 0, 0, 0);
        a0 += fexp2(fmaf(d0[0], LOG2E, -SHIFT2)) + fexp2(fmaf(d1[0], LOG2E, -SHIFT2));
        a1 += fexp2(fmaf(d0[1], LOG2E, -SHIFT2)) + fexp2(fmaf(d1[1], LOG2E, -SHIFT2));
        a2 += fexp2(fmaf(d0[2], LOG2E, -SHIFT2)) + fexp2(fmaf(d1[2], LOG2E, -SHIFT2));
        a3 += fexp2(fmaf(d0[3], LOG2E, -SHIFT2)) + fexp2(fmaf(d1[3], LOG2E, -SHIFT2));
        a0v = a2v;
        a1v = a3v;
    }
    float l = (a0 + a1) + (a2 + a3);
    l += __shfl_xor(l, 16);
    l += __shfl_xor(l, 32);
    if (q == 0)
        shl[(size_t)b * NN + jg] = -__log2f(l) - SHIFT2;
}

// --------------------------------------------------------------------------
// K4: O = h @ P^T + x.  Barrier-free main loop, register P.
// Block: 64 i x 256 c, 8 waves = (js 0..3 j-slice of 1024) x (ch c-half).
// Grid 512 (b = gid&7).  Per 32-j chunk per wave:
//   d_e/d_o = mfma32(g-frag, f-frag) x4 it  (S^T, once per (i,j) per ch)
//   pa[it] (B-frag, k=j 8q..8q+7) built from exp2(d)+pack via 8 shfl + 4 sel
//   acc[it][ct] += mfma32(hv[ct], pa[it])  (A = hm b128 row-gather, ct=0..7)
// hv/gfr prefetched one chunk ahead.  Epilogue: 4-round LDS reduce over js
// (64KB swizzled buffer), then out = O + x.
// --------------------------------------------------------------------------
__global__ __launch_bounds__(512, 2) void pass2_kernel(
    const float* __restrict__ x,
    const __half* __restrict__ ft, const __half* __restrict__ gt,
    const __half* __restrict__ hm, const float* __restrict__ shl,
    float* __restrict__ out)
{
    const int tid = threadIdx.x;
    const int w = tid >> 6, lane = tid & 63, col = lane & 15, q = lane >> 4;
    const int gid = blockIdx.x;
    const int b  = gid & 7;
    const int i0 = (gid >> 3) * 64;      // 64 i-tiles per batch
    const int js = w >> 1;               // j-slice (1024 j)
    const int ch = w & 1;                // c-half (128 c)
    const int cb = ch * 128;
    const int jbase = js * 1024;

    __shared__ float R[16384];           // [ch][c 128][i 64] swizzled, 64 KB

    const __half* gbase = gt + (size_t)b * NN * CQ;
    const __half* hbase = hm + (size_t)b * CC * NN;
    const float*  lb    = shl + (size_t)b * NN;

    // S B-frags (n = i), loop-invariant
    half8 ffr[4];
#pragma unroll
    for (int it = 0; it < 4; ++it)
        ffr[it] = *(const half8*)(const void*)(
            ft + ((size_t)b * NN + i0 + 16 * it + col) * CQ + q * 8);

    // hm A-frag offsets: row c = cb+16ct+col, k-offset 8q (elements)
    unsigned int hoff[8];
#pragma unroll
    for (int ct = 0; ct < 8; ++ct)
        hoff[ct] = (unsigned int)(cb + 16 * ct + col) * NN + 8 * q;

    f32x4 acc[4][8];
#pragma unroll
    for (int it = 0; it < 4; ++it)
#pragma unroll
        for (int ct = 0; ct < 8; ++ct)
            acc[it][ct] = (f32x4){0.f, 0.f, 0.f, 0.f};

    const f32x4 zero = {0.f, 0.f, 0.f, 0.f};
    const int srcA = (((2 * q) & 3) << 4) + col;      // shuffle source lanes
    const int srcB = (((2 * q + 1) & 3) << 4) + col;

    // prologue: chunk-0 operands
    half8 gfe = *(const half8*)(const void*)(gbase + (size_t)(jbase + col) * CQ + q * 8);
    half8 gfo = *(const half8*)(const void*)(gbase + (size_t)(jbase + 16 + col) * CQ + q * 8);
    half8 hv[8];
#pragma unroll
    for (int ct = 0; ct < 8; ++ct)
        hv[ct] = *(const half8*)(const void*)(hbase + hoff[ct] + jbase);

    for (int t = 0; t < 32; ++t) {
        const int j0 = jbase + t * 32;
        const int jn = jbase + ((t + 1) & 31) * 32;

        // S^T tiles: d[it] holds (j = j0(+16) + 4q + r, i = 16it + col)
        f32x4 de[4], dd[4];
#pragma unroll
        for (int it = 0; it < 4; ++it)
            de[it] = __builtin_amdgcn_mfma_f32_16x16x32_f16(gfe, ffr[it], zero, 0, 0, 0);
#pragma unroll
        for (int it = 0; it < 4; ++it)
            dd[it] = __builtin_amdgcn_mfma_f32_16x16x32_f16(gfo, ffr[it], zero, 0, 0, 0);

        // next-chunk g prefetch (wraps harmlessly on last iter)
        gfe = *(const half8*)(const void*)(gbase + (size_t)(jn + col) * CQ + q * 8);
        gfo = *(const half8*)(const void*)(gbase + (size_t)(jn + 16 + col) * CQ + q * 8);

        f32x4 sle = *(const f32x4*)(lb + j0 + 4 * q);
        f32x4 slo = *(const f32x4*)(lb + j0 + 16 + 4 * q);

        // P = exp2(S*log2e + shl[j]) -> f16 pairs -> redistribute q-layout
        // (4q+r per lane) into B-frag layout (8q..8q+7 per lane)
        half8 pa[4];
#pragma unroll
        for (int it = 0; it < 4; ++it) {
            int e0 = __builtin_bit_cast(int, __builtin_amdgcn_cvt_pkrtz(
                fexp2(fmaf(de[it][0], LOG2E, sle[0])),
                fexp2(fmaf(de[it][1], LOG2E, sle[1]))));
            int e1 = __builtin_bit_cast(int, __builtin_amdgcn_cvt_pkrtz(
                fexp2(fmaf(de[it][2], LOG2E, sle[2])),
                fexp2(fmaf(de[it][3], LOG2E, sle[3]))));
            int o0 = __builtin_bit_cast(int, __builtin_amdgcn_cvt_pkrtz(
                fexp2(fmaf(dd[it][0], LOG2E, slo[0])),
                fexp2(fmaf(dd[it][1], LOG2E, slo[1]))));
            int o1 = __builtin_bit_cast(int, __builtin_amdgcn_cvt_pkrtz(
                fexp2(fmaf(dd[it][2], LOG2E, slo[2])),
                fexp2(fmaf(dd[it][3], LOG2E, slo[3]))));
            int ae0 = __shfl(e0, srcA), ao0 = __shfl(o0, srcA);
            int ae1 = __shfl(e1, srcA), ao1 = __shfl(o1, srcA);
            int be0 = __shfl(e0, srcB), bo0 = __shfl(o0, srcB);
            int be1 = __shfl(e1, srcB), bo1 = __shfl(o1, srcB);
            intx4 pi;
            pi.x = (q < 2) ? ae0 : ao0;
            pi.y = (q < 2) ? ae1 : ao1;
            pi.z = (q < 2) ? be0 : bo0;
            pi.w = (q < 2) ? be1 : bo1;
            pa[it] = __builtin_bit_cast(half8, pi);
        }

        // O: acc[it][ct] += hm-frag x P-frag; reload hv[ct] for next chunk
#pragma unroll
        for (int ct = 0; ct < 8; ++ct) {
            half8 a = hv[ct];
#pragma unroll
            for (int it = 0; it < 4; ++it)
                acc[it][ct] = __builtin_amdgcn_mfma_f32_16x16x32_f16(
                    a, pa[it], acc[it][ct], 0, 0, 0);
            hv[ct] = *(const half8*)(const void*)(hbase + hoff[ct] + jn);
        }
    }

    // ---- epilogue: reduce partial O over the 4 js-waves via LDS ----
    // acc[it][ct][r] = O_partial[c = cb+16ct+4q+r][i = i0+16it+col]
#pragma unroll 1
    for (int round = 0; round < 4; ++round) {
        if (js == round) {
#pragma unroll
            for (int it = 0; it < 4; ++it) {
#pragma unroll
                for (int ct = 0; ct < 8; ++ct) {
#pragma unroll
                    for (int r = 0; r < 4; ++r) {
                        int cin = 16 * ct + 4 * q + r;
                        int idx = ch * 8192 + cin * 64 +
                                  ((16 * it + col) ^ ((cin & 7) << 3));
                        if (round == 0) R[idx] = acc[it][ct][r];
                        else            R[idx] += acc[it][ct][r];
                    }
                }
            }
        }
        __syncthreads();
    }

    // readback + residual + store: thread -> 8 (c, i-quad) groups
    const float* xb = x + (size_t)b * CC * NN;
    float* ob = out + (size_t)b * CC * NN;
#pragma unroll
    for (int r8 = 0; r8 < 8; ++r8) {
        int cg  = w * 32 + q * 8 + r8;       // 0..255
        int cl  = cg & 127, chh = cg >> 7;
        int il  = col * 4;
        int idx = chh * 8192 + cl * 64 + (il ^ ((cl & 7) << 3));
        f32x4 v = *(const f32x4*)&R[idx];
        size_t off = (size_t)cg * NN + i0 + il;
        f32x4 xv = __builtin_nontemporal_load((const f32x4*)(xb + off));
        f32x4 ov;
        ov.x = v.x + xv.x;
        ov.y = v.y + xv.y;
        ov.z = v.z + xv.z;
        ov.w = v.w + xv.w;
        __builtin_nontemporal_store(ov, (f32x4*)(ob + off));
    }
}

// ---------------------------------------------------------------------------
extern "C" void kernel_launch(void* const* d_in, const int* in_sizes, int n_in,
                              void* d_out, int out_size, void* d_ws, size_t ws_size,
                              hipStream_t stream)
{
    const float* x  = (const float*)d_in[0];
    const float* fw = (const float*)d_in[1];
    const float* fb = (const float*)d_in[2];
    const float* gw = (const float*)d_in[3];
    const float* gb = (const float*)d_in[4];
    const float* hw = (const float*)d_in[5];
    const float* hb = (const float*)d_in[6];
    float* out = (float*)d_out;

    char* ws = (char*)d_ws;
    __half* xt = (__half*)(ws);                          // 16,777,216
    __half* wf = (__half*)(ws + (size_t)16777216);       //    163,840 (pad 256K)
    __half* ft = (__half*)(ws + (size_t)17039360);       //  2,097,152
    __half* gt = (__half*)(ws + (size_t)19136512);       //  2,097,152
    __half* hm = (__half*)(ws + (size_t)21233664);       // 16,777,216
    float*  lv = (float*) (ws + (size_t)38010880);       //    131,072

    transpose_kernel<<<dim3(2368), dim3(256), 0, stream>>>(x, xt, fw, gw, hw, wf);
    proj_kernel<<<dim3(2560), dim3(256), 0, stream>>>(xt, wf, fb, gb, hb, ft, gt, hm);
    pass1_kernel<<<dim3(512), dim3(256), 0, stream>>>(ft, gt, lv);
    pass2_kernel<<<dim3(512), dim3(512), 0, stream>>>(x, ft, gt, hm, lv, out);
}

// Round 7
// 294.087 us; speedup vs baseline: 1.2881x; 1.2881x over previous
//
#include <hip/hip_runtime.h>
#include <hip/hip_fp16.h>
#include <cmath>

// ---------------------------------------------------------------------------
// Self_Attention: B=8, C=256, C_=32, H=W=64, N=4096, GAMMA=1.0
// R11: pass2 reverted to R5 (proven 155us champion; 5 structural attempts
// all landed worse).  Prep chain fused: transpose+proj -> tp_proj.
//   - tp_proj block (b, 64-pix tile): x staged via T[64][65] LDS transpose
//     into swizzled LDS xt_tile[64][256] f16 (XOR 8*(pix&7), same bank math
//     as R5's proven P-tile), then f/g (32 MFMA/wave) + h (128 MFMA/wave,
//     wave = 64-c_out slice) all read A/B frags from LDS.
//   - xt never touches HBM (saves 48MB round trip + proj's 5x L2 re-reads
//     + one kernel launch).  cvtw back as tiny separate kernel.
//   - pass1 = R9 (2x i-unroll, stores shl = -log2(l)-SHIFT2)
//   - pass2 = R5 with linv-mul replaced by shl addend (1 fmaf, same count)
// ws: wf 256K | ft 2M | gt 2M | hm 16M | shl 128K   (~21.4MB)
// ---------------------------------------------------------------------------

#define BN 8
#define CC 256
#define CQ 32
#define NN 4096

typedef _Float16 half8 __attribute__((ext_vector_type(8)));
typedef _Float16 half4v __attribute__((ext_vector_type(4)));
typedef float f32x4 __attribute__((ext_vector_type(4)));

static __device__ __forceinline__ float fexp2(float x) {
    return __builtin_amdgcn_exp2f(x);
}

#define LOG2E 1.44269504f
#define SHIFT2 28.8539008f   /* 20 * log2(e) */

// --------------------------------------------------------------------------
// K0: weight conversion f32 -> f16. 8192 + 8192 + 65536 = 81920 elements.
// --------------------------------------------------------------------------
__global__ __launch_bounds__(256) void cvtw_kernel(
    const float* __restrict__ fw, const float* __restrict__ gw,
    const float* __restrict__ hw, __half* __restrict__ wf16)
{
    int i = blockIdx.x * 256 + threadIdx.x;
    float v;
    if (i < 8192)       v = fw[i];
    else if (i < 16384) v = gw[i - 8192];
    else                v = hw[i - 16384];
    wf16[i] = __float2half(v);
}

// --------------------------------------------------------------------------
// K1: fused transpose + projections.  Grid 512: b = gid&7, nt = gid>>3.
// Phase A: x[b][c][n0..n0+63] f32 -> (T[64][65] LDS transpose, 4 rounds of
// 64 c) -> XT[pix][c^swz] f16 in LDS (swz = 8*(pix&7), half-granular XOR).
// Phase B1 (f/g): wave w owns pix group 16w+col; A = W_f/W_g (global, L1),
// B = XT rows -> ft/gt[pix][32].
// Phase B2 (h): wave w owns c_out 64w..64w+63; A = XT rows (pix tiles),
// B = W_h rows -> hm[c][n].
// --------------------------------------------------------------------------
__global__ __launch_bounds__(256) void tp_proj_kernel(
    const float* __restrict__ x, const __half* __restrict__ wf16,
    const float* __restrict__ fb, const float* __restrict__ gb,
    const float* __restrict__ hb,
    __half* __restrict__ ft, __half* __restrict__ gt, __half* __restrict__ hm)
{
    const int tid = threadIdx.x;
    const int w = tid >> 6, lane = tid & 63, col = lane & 15, q = lane >> 4;
    const int gid = blockIdx.x;
    const int b  = gid & 7;
    const int n0 = (gid >> 3) * 64;

    __shared__ float  T[64 * 65];        // 16.6 KB transpose staging
    __shared__ __half XT[64 * 256];      // 32 KB swizzled x-tile [pix][c]

    // ---- phase A: 4 rounds of 64-c transpose into XT ----
    const int u  = tid >> 4;             // 0..15
    const int n4 = (tid & 15) * 4;
    const int nn = w * 16 + (lane >> 2); // column-read pixel
    const int cc = (lane & 3) * 16;
    const int sA = 8 * (nn & 7);         // write-side swizzle
    for (int c4 = 0; c4 < 4; ++c4) {
        const int c0 = c4 * 64;
        const float* xb = x + ((size_t)b * CC + c0) * NN + n0;
#pragma unroll
        for (int r = 0; r < 4; ++r) {
            int c = r * 16 + u;
            f32x4 v = __builtin_nontemporal_load((const f32x4*)(xb + (size_t)c * NN + n4));
            T[c * 65 + n4 + 0] = v.x;
            T[c * 65 + n4 + 1] = v.y;
            T[c * 65 + n4 + 2] = v.z;
            T[c * 65 + n4 + 3] = v.w;
        }
        __syncthreads();
        half8 o0, o1;
#pragma unroll
        for (int k = 0; k < 8; ++k) {
            o0[k] = (_Float16)T[(cc + k) * 65 + nn];
            o1[k] = (_Float16)T[(cc + 8 + k) * 65 + nn];
        }
        *(half8*)(void*)(&XT[nn * 256 + ((c0 + cc) ^ sA)])     = o0;
        *(half8*)(void*)(&XT[nn * 256 + ((c0 + cc + 8) ^ sA)]) = o1;
        __syncthreads();
    }

    const f32x4 zero = {0.f, 0.f, 0.f, 0.f};
    const int sw = 8 * (col & 7);        // read-side swizzle (pix&7 = col&7)

    // ---- phase B1: f and g for pix group 16w+col ----
    {
        const __half* fw16 = wf16;
        const __half* gw16 = wf16 + 8192;
        f32x4 acc[4];
#pragma unroll
        for (int mt = 0; mt < 4; ++mt) acc[mt] = zero;
        const int pixl = 16 * w + col;
#pragma unroll
        for (int ks = 0; ks < 8; ++ks) {
            half8 bf = *(const half8*)(const void*)(
                &XT[pixl * 256 + ((ks * 32 + q * 8) ^ sw)]);
#pragma unroll
            for (int mt = 0; mt < 4; ++mt) {
                const __half* wp = (mt < 2) ? (fw16 + (16 * mt + col) * CC)
                                            : (gw16 + (16 * (mt - 2) + col) * CC);
                half8 af = *(const half8*)(const void*)(wp + ks * 32 + q * 8);
                acc[mt] = __builtin_amdgcn_mfma_f32_16x16x32_f16(af, bf, acc[mt], 0, 0, 0);
            }
        }
        const int pix = n0 + pixl;
#pragma unroll
        for (int mt = 0; mt < 4; ++mt) {
            const int mtl = mt & 1;
            const float* bsel = (mt < 2) ? fb : gb;
            __half* dsel = (mt < 2) ? ft : gt;
            half4v hv;
#pragma unroll
            for (int r = 0; r < 4; ++r)
                hv[r] = (_Float16)(acc[mt][r] + bsel[16 * mtl + 4 * q + r]);
            *(half4v*)(void*)(dsel + ((size_t)b * NN + pix) * CQ + 16 * mtl + 4 * q) = hv;
        }
    }

    // ---- phase B2: h for c_out slice 64w..64w+63 ----
    {
        const __half* hw16 = wf16 + 16384;
        f32x4 acc[4][4];                 // [mt = pix tile][ci = c_out tile]
#pragma unroll
        for (int mt = 0; mt < 4; ++mt)
#pragma unroll
            for (int ci = 0; ci < 4; ++ci) acc[mt][ci] = zero;
#pragma unroll
        for (int ks = 0; ks < 8; ++ks) {
            half8 af[4], bf[4];
#pragma unroll
            for (int mt = 0; mt < 4; ++mt)
                af[mt] = *(const half8*)(const void*)(
                    &XT[(16 * mt + col) * 256 + ((ks * 32 + q * 8) ^ sw)]);
#pragma unroll
            for (int ci = 0; ci < 4; ++ci)
                bf[ci] = *(const half8*)(const void*)(
                    hw16 + (size_t)(16 * (4 * w + ci) + col) * CC + ks * 32 + q * 8);
#pragma unroll
            for (int mt = 0; mt < 4; ++mt)
#pragma unroll
                for (int ci = 0; ci < 4; ++ci)
                    acc[mt][ci] = __builtin_amdgcn_mfma_f32_16x16x32_f16(
                        af[mt], bf[ci], acc[mt][ci], 0, 0, 0);
        }
#pragma unroll
        for (int ci = 0; ci < 4; ++ci) {
            const int c = 16 * (4 * w + ci) + col;
            const float bias = hb[c];
#pragma unroll
            for (int mt = 0; mt < 4; ++mt) {
                half4v hv;
#pragma unroll
                for (int r = 0; r < 4; ++r)
                    hv[r] = (_Float16)(acc[mt][ci][r] + bias);
                *(half4v*)(void*)(hm + ((size_t)b * CC + c) * NN + n0 + 16 * mt + 4 * q) = hv;
            }
        }
    }
}

// --------------------------------------------------------------------------
// K3: per-column softmax log-denominator with constant shift:
// shl[b][j] = -log2( sum_i exp2(S_ij*log2e - SHIFT2) ) - SHIFT2
// 2x i-unroll: two independent MFMAs in flight.
// --------------------------------------------------------------------------
__global__ __launch_bounds__(256) void pass1_kernel(
    const __half* __restrict__ ft, const __half* __restrict__ gt,
    float* __restrict__ shl)
{
    const int tid = threadIdx.x;
    const int w = tid >> 6, lane = tid & 63, col = lane & 15, q = lane >> 4;
    const int gid = blockIdx.x;
    const int b = gid & 7;
    const int jg = (gid >> 3) * 64 + 16 * w + col;

    const __half* fbase = ft + (size_t)b * NN * CQ;
    half8 gfrag = *(const half8*)(const void*)(gt + ((size_t)b * NN + jg) * CQ + q * 8);

    float a0 = 0.f, a1 = 0.f, a2 = 0.f, a3 = 0.f;
    const f32x4 zero = {0.f, 0.f, 0.f, 0.f};

    half8 a0v = *(const half8*)(const void*)(fbase + (size_t)col * CQ + q * 8);
    half8 a1v = *(const half8*)(const void*)(fbase + (size_t)(16 + col) * CQ + q * 8);
    for (int i0 = 0; i0 < NN; i0 += 32) {
        int i_n = (i0 + 32) & (NN - 1);
        half8 a2v = *(const half8*)(const void*)(fbase + (size_t)(i_n + col) * CQ + q * 8);
        half8 a3v = *(const half8*)(const void*)(fbase + (size_t)(i_n + 16 + col) * CQ + q * 8);
        f32x4 d0 = __builtin_amdgcn_mfma_f32_16x16x32_f16(a0v, gfrag, zero, 0, 0, 0);
        f32x4 d1 = __builtin_amdgcn_mfma_f32_16x16x32_f16(a1v, gfrag, zero, 0, 0, 0);
        a0 += fexp2(fmaf(d0[0], LOG2E, -SHIFT2)) + fexp2(fmaf(d1[0], LOG2E, -SHIFT2));
        a1 += fexp2(fmaf(d0[1], LOG2E, -SHIFT2)) + fexp2(fmaf(d1[1], LOG2E, -SHIFT2));
        a2 += fexp2(fmaf(d0[2], LOG2E, -SHIFT2)) + fexp2(fmaf(d1[2], LOG2E, -SHIFT2));
        a3 += fexp2(fmaf(d0[3], LOG2E, -SHIFT2)) + fexp2(fmaf(d1[3], LOG2E, -SHIFT2));
        a0v = a2v;
        a1v = a3v;
    }
    float l = (a0 + a1) + (a2 + a3);
    l += __shfl_xor(l, 16);
    l += __shfl_xor(l, 32);
    if (q == 0)
        shl[(size_t)b * NN + jg] = -__log2f(l) - SHIFT2;
}

// --------------------------------------------------------------------------
// K4: O = h @ P^T + x.  R5 structure verbatim (155us champion):
// Block 64 i x 256 c (4 waves x 64c, ns=4), j-step 64, grid 512, LB(256,2).
// Only change: linv multiply replaced by shl addend in the exp2.
// --------------------------------------------------------------------------
__global__ __launch_bounds__(256, 2) void pass2_kernel(
    const float* __restrict__ x,
    const __half* __restrict__ ft, const __half* __restrict__ gt,
    const __half* __restrict__ hm, const float* __restrict__ shl,
    float* __restrict__ out)
{
    const int tid = threadIdx.x;
    const int w = tid >> 6, lane = tid & 63, col = lane & 15, q = lane >> 4;
    const int gid = blockIdx.x;
    const int b  = gid & 7;
    const int i0 = (gid >> 3) * 64;          // 64 i-tiles per batch
    const int cb = 64 * w;                   // wave c-slice: 64 channels

    __shared__ __half P[2][64 * 64];

    const __half* gbase = gt + (size_t)b * NN * CQ;
    const __half* hbase = hm + (size_t)b * CC * NN;
    const float*  lb    = shl + (size_t)b * NN;

    // loop-invariant f B-frags (n = i)
    half8 ffr[4];
#pragma unroll
    for (int it = 0; it < 4; ++it)
        ffr[it] = *(const half8*)(const void*)(ft + ((size_t)b * NN + i0 + 16 * it + col) * CQ + q * 8);

    f32x4 acc[4][4];
#pragma unroll
    for (int ms = 0; ms < 4; ++ms)
#pragma unroll
        for (int ns = 0; ns < 4; ++ns)
            acc[ms][ns] = (f32x4){0.f, 0.f, 0.f, 0.f};

    const f32x4 zero = {0.f, 0.f, 0.f, 0.f};
    const int jml = 16 * w + 4 * q;          // this lane's j offset in the step
    const int sw  = 8 * (col & 7);           // P swizzle for this lane's rows

    // prologue prefetch (step 0)
    half8 gfr = *(const half8*)(const void*)(gbase + (size_t)(16 * w + col) * CQ + q * 8);
    f32x4 sl  = *(const f32x4*)(lb + jml);

    int buf = 0;
    for (int j0 = 0; j0 < NN; j0 += 64, buf ^= 1) {
        // current-step O-phase B-frags (L2-resident hm), ns=4 x ks=2
        half8 hv[4][2];
#pragma unroll
        for (int ns = 0; ns < 4; ++ns)
#pragma unroll
            for (int ks = 0; ks < 2; ++ks)
                hv[ns][ks] = *(const half8*)(const void*)(
                    hbase + (size_t)(cb + 16 * ns + col) * NN + j0 + ks * 32 + q * 8);

        // S^T tiles: rows j = j0+16w+4q+r, cols i = 16it+col
        f32x4 d[4];
#pragma unroll
        for (int it = 0; it < 4; ++it)
            d[it] = __builtin_amdgcn_mfma_f32_16x16x32_f16(gfr, ffr[it], zero, 0, 0, 0);

        // next-step prefetch (wraps harmlessly on last iter)
        const int jn = (j0 + 64) & (NN - 1);
        half8 gfr_n = *(const half8*)(const void*)(gbase + (size_t)(jn + 16 * w + col) * CQ + q * 8);
        f32x4 sl_n  = *(const f32x4*)(lb + jn + jml);

        // P = exp2(S*log2e + shl[j])  -> swizzled LDS
        __half* Pb = &P[buf][0];
#pragma unroll
        for (int it = 0; it < 4; ++it) {
            half4v pv;
            pv[0] = (_Float16)fexp2(fmaf(d[it][0], LOG2E, sl[0]));
            pv[1] = (_Float16)fexp2(fmaf(d[it][1], LOG2E, sl[1]));
            pv[2] = (_Float16)fexp2(fmaf(d[it][2], LOG2E, sl[2]));
            pv[3] = (_Float16)fexp2(fmaf(d[it][3], LOG2E, sl[3]));
            *(half4v*)(void*)(Pb + (16 * it + col) * 64 + (jml ^ sw)) = pv;
        }
        __syncthreads();

        // O: A = P (swizzled b128 reads, each feeds 4 MFMAs), B = hv
#pragma unroll
        for (int ks = 0; ks < 2; ++ks) {
            half8 af[4];
#pragma unroll
            for (int ms = 0; ms < 4; ++ms)
                af[ms] = *(const half8*)(const void*)(
                    Pb + (16 * ms + col) * 64 + ((ks * 32 + q * 8) ^ sw));
#pragma unroll
            for (int ms = 0; ms < 4; ++ms)
#pragma unroll
                for (int ns = 0; ns < 4; ++ns)
                    acc[ms][ns] = __builtin_amdgcn_mfma_f32_16x16x32_f16(
                        af[ms], hv[ns][ks], acc[ms][ns], 0, 0, 0);
        }
        gfr = gfr_n;
        sl  = sl_n;
    }

    // epilogue: out = O + x (nontemporal both ways; GAMMA = 1)
    const float* xb = x + (size_t)b * CC * NN;
    float* ob = out + (size_t)b * CC * NN;
#pragma unroll
    for (int ms = 0; ms < 4; ++ms) {
#pragma unroll
        for (int ns = 0; ns < 4; ++ns) {
            int c  = cb + 16 * ns + col;
            int ii = i0 + 16 * ms + 4 * q;
            size_t off = (size_t)c * NN + ii;
            f32x4 xv = __builtin_nontemporal_load((const f32x4*)(xb + off));
            f32x4 ov;
            ov.x = acc[ms][ns][0] + xv.x;
            ov.y = acc[ms][ns][1] + xv.y;
            ov.z = acc[ms][ns][2] + xv.z;
            ov.w = acc[ms][ns][3] + xv.w;
            __builtin_nontemporal_store(ov, (f32x4*)(ob + off));
        }
    }
}

// ---------------------------------------------------------------------------
extern "C" void kernel_launch(void* const* d_in, const int* in_sizes, int n_in,
                              void* d_out, int out_size, void* d_ws, size_t ws_size,
                              hipStream_t stream)
{
    const float* x  = (const float*)d_in[0];
    const float* fw = (const float*)d_in[1];
    const float* fb = (const float*)d_in[2];
    const float* gw = (const float*)d_in[3];
    const float* gb = (const float*)d_in[4];
    const float* hw = (const float*)d_in[5];
    const float* hb = (const float*)d_in[6];
    float* out = (float*)d_out;

    char* ws = (char*)d_ws;
    __half* wf = (__half*)(ws);                          //   163,840 (pad 256K)
    __half* ft = (__half*)(ws + (size_t)262144);         // 2,097,152
    __half* gt = (__half*)(ws + (size_t)2359296);        // 2,097,152
    __half* hm = (__half*)(ws + (size_t)4456448);        // 16,777,216
    float*  lv = (float*) (ws + (size_t)21233664);       //   131,072

    cvtw_kernel<<<dim3(320), dim3(256), 0, stream>>>(fw, gw, hw, wf);
    tp_proj_kernel<<<dim3(512), dim3(256), 0, stream>>>(x, wf, fb, gb, hb, ft, gt, hm);
    pass1_kernel<<<dim3(512), dim3(256), 0, stream>>>(ft, gt, lv);
    pass2_kernel<<<dim3(512), dim3(256), 0, stream>>>(x, ft, gt, hm, lv, out);
}

// Round 8
// 289.846 us; speedup vs baseline: 1.3070x; 1.0146x over previous
//
#include <hip/hip_runtime.h>
#include <hip/hip_fp16.h>
#include <cmath>

// ---------------------------------------------------------------------------
// Self_Attention: B=8, C=256, C_=32, H=W=64, N=4096, GAMMA=1.0
// R12 = R11 with the prep chain parallelized (prep was ~140us vs ~35 roofline;
// pass2 is a confirmed local optimum at ~154us and is untouched):
//   - pass1 split into pass1a (grid 2048: i-range quartered, partial column
//     sums to lpart[iq][b][j], no atomics) + pass1b finalize (32 blocks,
//     shl = -log2(sum of 4 partials) - SHIFT2).  4x block count attacks the
//     serial 128-iter latency chain.
//   - tp_proj: all 16 x-tile f32x4 loads prefetched into registers before
//     round 0 (barrier memory-clobber blocks compiler hoisting; explicit
//     prefetch takes cold-HBM latency off rounds 1-3's critical path).
//   - cvtw, pass2 byte-identical to R11.
// ws: wf 256K | ft 2M | gt 2M | hm 16M | shl 128K | lpart 512K  (~22MB)
// ---------------------------------------------------------------------------

#define BN 8
#define CC 256
#define CQ 32
#define NN 4096

typedef _Float16 half8 __attribute__((ext_vector_type(8)));
typedef _Float16 half4v __attribute__((ext_vector_type(4)));
typedef float f32x4 __attribute__((ext_vector_type(4)));

static __device__ __forceinline__ float fexp2(float x) {
    return __builtin_amdgcn_exp2f(x);
}

#define LOG2E 1.44269504f
#define SHIFT2 28.8539008f   /* 20 * log2(e) */

// --------------------------------------------------------------------------
// K0: weight conversion f32 -> f16. 8192 + 8192 + 65536 = 81920 elements.
// --------------------------------------------------------------------------
__global__ __launch_bounds__(256) void cvtw_kernel(
    const float* __restrict__ fw, const float* __restrict__ gw,
    const float* __restrict__ hw, __half* __restrict__ wf16)
{
    int i = blockIdx.x * 256 + threadIdx.x;
    float v;
    if (i < 8192)       v = fw[i];
    else if (i < 16384) v = gw[i - 8192];
    else                v = hw[i - 16384];
    wf16[i] = __float2half(v);
}

// --------------------------------------------------------------------------
// K1: fused transpose + projections.  Grid 512: b = gid&7, nt = gid>>3.
// Phase A: x-tile prefetched whole (16 f32x4/lane), then 4 rounds of
// T[64][65] transpose -> XT[pix][c^swz] f16 (swz = 8*(pix&7)).
// Phase B1 (f/g): wave w owns pix group 16w+col -> ft/gt[pix][32].
// Phase B2 (h): wave w owns c_out 64w..64w+63 -> hm[c][n].
// --------------------------------------------------------------------------
__global__ __launch_bounds__(256) void tp_proj_kernel(
    const float* __restrict__ x, const __half* __restrict__ wf16,
    const float* __restrict__ fb, const float* __restrict__ gb,
    const float* __restrict__ hb,
    __half* __restrict__ ft, __half* __restrict__ gt, __half* __restrict__ hm)
{
    const int tid = threadIdx.x;
    const int w = tid >> 6, lane = tid & 63, col = lane & 15, q = lane >> 4;
    const int gid = blockIdx.x;
    const int b  = gid & 7;
    const int n0 = (gid >> 3) * 64;

    __shared__ float  T[64 * 65];        // 16.6 KB transpose staging
    __shared__ __half XT[64 * 256];      // 32 KB swizzled x-tile [pix][c]

    // ---- phase A: prefetch entire x-tile, then 4 transpose rounds ----
    const int u  = tid >> 4;             // 0..15
    const int n4 = (tid & 15) * 4;
    const int nn = w * 16 + (lane >> 2); // column-read pixel
    const int cc = (lane & 3) * 16;
    const int sA = 8 * (nn & 7);         // write-side swizzle

    f32x4 vx[4][4];
    const float* xb = x + (size_t)b * CC * NN + n0;
#pragma unroll
    for (int c4 = 0; c4 < 4; ++c4)
#pragma unroll
        for (int r = 0; r < 4; ++r)
            vx[c4][r] = __builtin_nontemporal_load(
                (const f32x4*)(xb + (size_t)(c4 * 64 + r * 16 + u) * NN + n4));

#pragma unroll
    for (int c4 = 0; c4 < 4; ++c4) {
        const int c0 = c4 * 64;
#pragma unroll
        for (int r = 0; r < 4; ++r) {
            int c = r * 16 + u;
            T[c * 65 + n4 + 0] = vx[c4][r].x;
            T[c * 65 + n4 + 1] = vx[c4][r].y;
            T[c * 65 + n4 + 2] = vx[c4][r].z;
            T[c * 65 + n4 + 3] = vx[c4][r].w;
        }
        __syncthreads();
        half8 o0, o1;
#pragma unroll
        for (int k = 0; k < 8; ++k) {
            o0[k] = (_Float16)T[(cc + k) * 65 + nn];
            o1[k] = (_Float16)T[(cc + 8 + k) * 65 + nn];
        }
        *(half8*)(void*)(&XT[nn * 256 + ((c0 + cc) ^ sA)])     = o0;
        *(half8*)(void*)(&XT[nn * 256 + ((c0 + cc + 8) ^ sA)]) = o1;
        __syncthreads();
    }

    const f32x4 zero = {0.f, 0.f, 0.f, 0.f};
    const int sw = 8 * (col & 7);        // read-side swizzle (pix&7 = col&7)

    // ---- phase B1: f and g for pix group 16w+col ----
    {
        const __half* fw16 = wf16;
        const __half* gw16 = wf16 + 8192;
        f32x4 acc[4];
#pragma unroll
        for (int mt = 0; mt < 4; ++mt) acc[mt] = zero;
        const int pixl = 16 * w + col;
#pragma unroll
        for (int ks = 0; ks < 8; ++ks) {
            half8 bf = *(const half8*)(const void*)(
                &XT[pixl * 256 + ((ks * 32 + q * 8) ^ sw)]);
#pragma unroll
            for (int mt = 0; mt < 4; ++mt) {
                const __half* wp = (mt < 2) ? (fw16 + (16 * mt + col) * CC)
                                            : (gw16 + (16 * (mt - 2) + col) * CC);
                half8 af = *(const half8*)(const void*)(wp + ks * 32 + q * 8);
                acc[mt] = __builtin_amdgcn_mfma_f32_16x16x32_f16(af, bf, acc[mt], 0, 0, 0);
            }
        }
        const int pix = n0 + pixl;
#pragma unroll
        for (int mt = 0; mt < 4; ++mt) {
            const int mtl = mt & 1;
            const float* bsel = (mt < 2) ? fb : gb;
            __half* dsel = (mt < 2) ? ft : gt;
            half4v hv;
#pragma unroll
            for (int r = 0; r < 4; ++r)
                hv[r] = (_Float16)(acc[mt][r] + bsel[16 * mtl + 4 * q + r]);
            *(half4v*)(void*)(dsel + ((size_t)b * NN + pix) * CQ + 16 * mtl + 4 * q) = hv;
        }
    }

    // ---- phase B2: h for c_out slice 64w..64w+63 ----
    {
        const __half* hw16 = wf16 + 16384;
        f32x4 acc[4][4];                 // [mt = pix tile][ci = c_out tile]
#pragma unroll
        for (int mt = 0; mt < 4; ++mt)
#pragma unroll
            for (int ci = 0; ci < 4; ++ci) acc[mt][ci] = zero;
#pragma unroll
        for (int ks = 0; ks < 8; ++ks) {
            half8 af[4], bf[4];
#pragma unroll
            for (int mt = 0; mt < 4; ++mt)
                af[mt] = *(const half8*)(const void*)(
                    &XT[(16 * mt + col) * 256 + ((ks * 32 + q * 8) ^ sw)]);
#pragma unroll
            for (int ci = 0; ci < 4; ++ci)
                bf[ci] = *(const half8*)(const void*)(
                    hw16 + (size_t)(16 * (4 * w + ci) + col) * CC + ks * 32 + q * 8);
#pragma unroll
            for (int mt = 0; mt < 4; ++mt)
#pragma unroll
                for (int ci = 0; ci < 4; ++ci)
                    acc[mt][ci] = __builtin_amdgcn_mfma_f32_16x16x32_f16(
                        af[mt], bf[ci], acc[mt][ci], 0, 0, 0);
        }
#pragma unroll
        for (int ci = 0; ci < 4; ++ci) {
            const int c = 16 * (4 * w + ci) + col;
            const float bias = hb[c];
#pragma unroll
            for (int mt = 0; mt < 4; ++mt) {
                half4v hv;
#pragma unroll
                for (int r = 0; r < 4; ++r)
                    hv[r] = (_Float16)(acc[mt][ci][r] + bias);
                *(half4v*)(void*)(hm + ((size_t)b * CC + c) * NN + n0 + 16 * mt + 4 * q) = hv;
            }
        }
    }
}

// --------------------------------------------------------------------------
// K3a: partial softmax column sums.  Grid 2048: b = gid&7, jt = (gid>>3)&63,
// iq = gid>>9 (i-quarter).  Each wave: 16 j x 1024 i (32 iters, 2-MFMA
// unroll).  lpart[iq][b][j] = sum_{i in quarter} exp2(S*log2e - SHIFT2).
// --------------------------------------------------------------------------
__global__ __launch_bounds__(256) void pass1a_kernel(
    const __half* __restrict__ ft, const __half* __restrict__ gt,
    float* __restrict__ lpart)
{
    const int tid = threadIdx.x;
    const int w = tid >> 6, lane = tid & 63, col = lane & 15, q = lane >> 4;
    const int gid = blockIdx.x;
    const int b  = gid & 7;
    const int jt = (gid >> 3) & 63;
    const int iq = gid >> 9;             // 0..3
    const int jg = jt * 64 + 16 * w + col;
    const int ibase = iq * 1024;

    const __half* fbase = ft + (size_t)b * NN * CQ;
    half8 gfrag = *(const half8*)(const void*)(gt + ((size_t)b * NN + jg) * CQ + q * 8);

    float a0 = 0.f, a1 = 0.f, a2 = 0.f, a3 = 0.f;
    const f32x4 zero = {0.f, 0.f, 0.f, 0.f};

    half8 a0v = *(const half8*)(const void*)(fbase + (size_t)(ibase + col) * CQ + q * 8);
    half8 a1v = *(const half8*)(const void*)(fbase + (size_t)(ibase + 16 + col) * CQ + q * 8);
    for (int t = 0; t < 32; ++t) {
        int i_n = ibase + ((t + 1) & 31) * 32;
        half8 a2v = *(const half8*)(const void*)(fbase + (size_t)(i_n + col) * CQ + q * 8);
        half8 a3v = *(const half8*)(const void*)(fbase + (size_t)(i_n + 16 + col) * CQ + q * 8);
        f32x4 d0 = __builtin_amdgcn_mfma_f32_16x16x32_f16(a0v, gfrag, zero, 0, 0, 0);
        f32x4 d1 = __builtin_amdgcn_mfma_f32_16x16x32_f16(a1v, gfrag, zero, 0, 0, 0);
        a0 += fexp2(fmaf(d0[0], LOG2E, -SHIFT2)) + fexp2(fmaf(d1[0], LOG2E, -SHIFT2));
        a1 += fexp2(fmaf(d0[1], LOG2E, -SHIFT2)) + fexp2(fmaf(d1[1], LOG2E, -SHIFT2));
        a2 += fexp2(fmaf(d0[2], LOG2E, -SHIFT2)) + fexp2(fmaf(d1[2], LOG2E, -SHIFT2));
        a3 += fexp2(fmaf(d0[3], LOG2E, -SHIFT2)) + fexp2(fmaf(d1[3], LOG2E, -SHIFT2));
        a0v = a2v;
        a1v = a3v;
    }
    float l = (a0 + a1) + (a2 + a3);
    l += __shfl_xor(l, 16);
    l += __shfl_xor(l, 32);
    if (q == 0)
        lpart[((size_t)iq * BN + b) * NN + jg] = l;
}

// --------------------------------------------------------------------------
// K3b: finalize shl[b][j] = -log2(sum of 4 partials) - SHIFT2.
// 32768 outputs; grid 32 x 256 thr x 4/thread (f32x4).
// --------------------------------------------------------------------------
__global__ __launch_bounds__(256) void pass1b_kernel(
    const float* __restrict__ lpart, float* __restrict__ shl)
{
    const int i4 = (blockIdx.x * 256 + threadIdx.x) * 4;
    f32x4 s0 = *(const f32x4*)(lpart + i4);
    f32x4 s1 = *(const f32x4*)(lpart + 1 * BN * NN + i4);
    f32x4 s2 = *(const f32x4*)(lpart + 2 * BN * NN + i4);
    f32x4 s3 = *(const f32x4*)(lpart + 3 * BN * NN + i4);
    f32x4 o;
    o.x = -__log2f((s0.x + s1.x) + (s2.x + s3.x)) - SHIFT2;
    o.y = -__log2f((s0.y + s1.y) + (s2.y + s3.y)) - SHIFT2;
    o.z = -__log2f((s0.z + s1.z) + (s2.z + s3.z)) - SHIFT2;
    o.w = -__log2f((s0.w + s1.w) + (s2.w + s3.w)) - SHIFT2;
    *(f32x4*)(shl + i4) = o;
}

// --------------------------------------------------------------------------
// K4: O = h @ P^T + x.  R5 structure verbatim (154us champion):
// Block 64 i x 256 c (4 waves x 64c, ns=4), j-step 64, grid 512, LB(256,2).
// --------------------------------------------------------------------------
__global__ __launch_bounds__(256, 2) void pass2_kernel(
    const float* __restrict__ x,
    const __half* __restrict__ ft, const __half* __restrict__ gt,
    const __half* __restrict__ hm, const float* __restrict__ shl,
    float* __restrict__ out)
{
    const int tid = threadIdx.x;
    const int w = tid >> 6, lane = tid & 63, col = lane & 15, q = lane >> 4;
    const int gid = blockIdx.x;
    const int b  = gid & 7;
    const int i0 = (gid >> 3) * 64;          // 64 i-tiles per batch
    const int cb = 64 * w;                   // wave c-slice: 64 channels

    __shared__ __half P[2][64 * 64];

    const __half* gbase = gt + (size_t)b * NN * CQ;
    const __half* hbase = hm + (size_t)b * CC * NN;
    const float*  lb    = shl + (size_t)b * NN;

    // loop-invariant f B-frags (n = i)
    half8 ffr[4];
#pragma unroll
    for (int it = 0; it < 4; ++it)
        ffr[it] = *(const half8*)(const void*)(ft + ((size_t)b * NN + i0 + 16 * it + col) * CQ + q * 8);

    f32x4 acc[4][4];
#pragma unroll
    for (int ms = 0; ms < 4; ++ms)
#pragma unroll
        for (int ns = 0; ns < 4; ++ns)
            acc[ms][ns] = (f32x4){0.f, 0.f, 0.f, 0.f};

    const f32x4 zero = {0.f, 0.f, 0.f, 0.f};
    const int jml = 16 * w + 4 * q;          // this lane's j offset in the step
    const int sw  = 8 * (col & 7);           // P swizzle for this lane's rows

    // prologue prefetch (step 0)
    half8 gfr = *(const half8*)(const void*)(gbase + (size_t)(16 * w + col) * CQ + q * 8);
    f32x4 sl  = *(const f32x4*)(lb + jml);

    int buf = 0;
    for (int j0 = 0; j0 < NN; j0 += 64, buf ^= 1) {
        // current-step O-phase B-frags (L2-resident hm), ns=4 x ks=2
        half8 hv[4][2];
#pragma unroll
        for (int ns = 0; ns < 4; ++ns)
#pragma unroll
            for (int ks = 0; ks < 2; ++ks)
                hv[ns][ks] = *(const half8*)(const void*)(
                    hbase + (size_t)(cb + 16 * ns + col) * NN + j0 + ks * 32 + q * 8);

        // S^T tiles: rows j = j0+16w+4q+r, cols i = 16it+col
        f32x4 d[4];
#pragma unroll
        for (int it = 0; it < 4; ++it)
            d[it] = __builtin_amdgcn_mfma_f32_16x16x32_f16(gfr, ffr[it], zero, 0, 0, 0);

        // next-step prefetch (wraps harmlessly on last iter)
        const int jn = (j0 + 64) & (NN - 1);
        half8 gfr_n = *(const half8*)(const void*)(gbase + (size_t)(jn + 16 * w + col) * CQ + q * 8);
        f32x4 sl_n  = *(const f32x4*)(lb + jn + jml);

        // P = exp2(S*log2e + shl[j])  -> swizzled LDS
        __half* Pb = &P[buf][0];
#pragma unroll
        for (int it = 0; it < 4; ++it) {
            half4v pv;
            pv[0] = (_Float16)fexp2(fmaf(d[it][0], LOG2E, sl[0]));
            pv[1] = (_Float16)fexp2(fmaf(d[it][1], LOG2E, sl[1]));
            pv[2] = (_Float16)fexp2(fmaf(d[it][2], LOG2E, sl[2]));
            pv[3] = (_Float16)fexp2(fmaf(d[it][3], LOG2E, sl[3]));
            *(half4v*)(void*)(Pb + (16 * it + col) * 64 + (jml ^ sw)) = pv;
        }
        __syncthreads();

        // O: A = P (swizzled b128 reads, each feeds 4 MFMAs), B = hv
#pragma unroll
        for (int ks = 0; ks < 2; ++ks) {
            half8 af[4];
#pragma unroll
            for (int ms = 0; ms < 4; ++ms)
                af[ms] = *(const half8*)(const void*)(
                    Pb + (16 * ms + col) * 64 + ((ks * 32 + q * 8) ^ sw));
#pragma unroll
            for (int ms = 0; ms < 4; ++ms)
#pragma unroll
                for (int ns = 0; ns < 4; ++ns)
                    acc[ms][ns] = __builtin_amdgcn_mfma_f32_16x16x32_f16(
                        af[ms], hv[ns][ks], acc[ms][ns], 0, 0, 0);
        }
        gfr = gfr_n;
        sl  = sl_n;
    }

    // epilogue: out = O + x (nontemporal both ways; GAMMA = 1)
    const float* xb = x + (size_t)b * CC * NN;
    float* ob = out + (size_t)b * CC * NN;
#pragma unroll
    for (int ms = 0; ms < 4; ++ms) {
#pragma unroll
        for (int ns = 0; ns < 4; ++ns) {
            int c  = cb + 16 * ns + col;
            int ii = i0 + 16 * ms + 4 * q;
            size_t off = (size_t)c * NN + ii;
            f32x4 xv = __builtin_nontemporal_load((const f32x4*)(xb + off));
            f32x4 ov;
            ov.x = acc[ms][ns][0] + xv.x;
            ov.y = acc[ms][ns][1] + xv.y;
            ov.z = acc[ms][ns][2] + xv.z;
            ov.w = acc[ms][ns][3] + xv.w;
            __builtin_nontemporal_store(ov, (f32x4*)(ob + off));
        }
    }
}

// ---------------------------------------------------------------------------
extern "C" void kernel_launch(void* const* d_in, const int* in_sizes, int n_in,
                              void* d_out, int out_size, void* d_ws, size_t ws_size,
                              hipStream_t stream)
{
    const float* x  = (const float*)d_in[0];
    const float* fw = (const float*)d_in[1];
    const float* fb = (const float*)d_in[2];
    const float* gw = (const float*)d_in[3];
    const float* gb = (const float*)d_in[4];
    const float* hw = (const float*)d_in[5];
    const float* hb = (const float*)d_in[6];
    float* out = (float*)d_out;

    char* ws = (char*)d_ws;
    __half* wf = (__half*)(ws);                          //   163,840 (pad 256K)
    __half* ft = (__half*)(ws + (size_t)262144);         // 2,097,152
    __half* gt = (__half*)(ws + (size_t)2359296);        // 2,097,152
    __half* hm = (__half*)(ws + (size_t)4456448);        // 16,777,216
    float*  lv = (float*) (ws + (size_t)21233664);       //   131,072 (shl)
    float*  lp = (float*) (ws + (size_t)21364736);       //   524,288 (lpart)

    cvtw_kernel<<<dim3(320), dim3(256), 0, stream>>>(fw, gw, hw, wf);
    tp_proj_kernel<<<dim3(512), dim3(256), 0, stream>>>(x, wf, fb, gb, hb, ft, gt, hm);
    pass1a_kernel<<<dim3(2048), dim3(256), 0, stream>>>(ft, gt, lp);
    pass1b_kernel<<<dim3(32), dim3(256), 0, stream>>>(lp, lv);
    pass2_kernel<<<dim3(512), dim3(256), 0, stream>>>(x, ft, gt, hm, lv, out);
}